// Round 3
// baseline (160.122 us; speedup 1.0000x reference)
//
#include <hip/hip_runtime.h>
#include <math.h>

typedef unsigned short u16;
typedef short bf16x8 __attribute__((ext_vector_type(8)));
typedef float f32x4 __attribute__((ext_vector_type(4)));

// Workspace byte offsets
#define XT_B   0u          // bf16 [4][64][64][128]  NHWC x
#define WF_B   4194304u    // bf16 [9][8][4][64][8]  main A-frags (t,mt,ks,lane,j)
#define WRF_B  4489216u    // bf16 [36][2][64][8]    offmask A-frags (ks',mt,lane,j)
#define BNS_B  4562944u    // f32 [128] folded BN scale
#define BNB_B  4563456u    // f32 [128] folded BN shift

__device__ __forceinline__ float bf2f(u16 u) {
  union { unsigned int i; float f; } v; v.i = ((unsigned int)u) << 16; return v.f;
}
__device__ __forceinline__ u16 f2bf(float f) {
  union { float f; unsigned int i; } v; v.f = f;
  unsigned int i = v.i;
  return (u16)((i + 0x7fffu + ((i >> 16) & 1u)) >> 16);  // RNE
}
// bf16 pair packed in a uint: low u16 = channel c, high u16 = channel c+1
__device__ __forceinline__ float ulo(unsigned int u) {
  union { unsigned int i; float f; } v; v.i = u << 16; return v.f;
}
__device__ __forceinline__ float uhi(unsigned int u) {
  union { unsigned int i; float f; } v; v.i = u & 0xffff0000u; return v.f;
}
__device__ __forceinline__ unsigned int pk(float lo, float hi) {
  return (unsigned int)f2bf(lo) | ((unsigned int)f2bf(hi) << 16);
}

// ---------------------------------------------------------------------------
// prep: x -> bf16 NHWC (LDS-tiled transpose, 512 blocks), weight frag
// shuffles, BN fold. Grid = 1233 blocks x 256.
// ---------------------------------------------------------------------------
__global__ __launch_bounds__(256) void prep_kernel(
    const float* __restrict__ x,   const float* __restrict__ ow,
    const float* __restrict__ mw,  const float* __restrict__ wgt,
    const float* __restrict__ gam, const float* __restrict__ bet,
    const float* __restrict__ mean,const float* __restrict__ var,
    char* __restrict__ wsb) {
  int blk = blockIdx.x, tid = threadIdx.x;
  if (blk < 512) {  // transpose half a (b,y) plane: 128c x 32x -> 32x x 128c
    __shared__ u16 tile[32][132];  // pitch 132: 8B-aligned rows, <=2-way banks
    int b = blk >> 7, y = (blk >> 1) & 63, xh = blk & 1;
    const float* src = x + (size_t)(b * 128 * 64 + y) * 64 + xh * 32;
#pragma unroll
    for (int rep = 0; rep < 16; ++rep) {
      int flat = rep * 256 + tid;        // 4096 = 128c x 32x
      int c = flat >> 5, xxl = flat & 31;  // lanes vary xx -> coalesced reads
      tile[xxl][c] = f2bf(src[c * 4096 + xxl]);
    }
    __syncthreads();
    u16* dst = (u16*)(wsb + XT_B) + ((b * 64 + y) * 64 + xh * 32) * 128;
#pragma unroll
    for (int rep = 0; rep < 4; ++rep) {
      int flat = rep * 256 + tid;        // 1024 = 32x x 32 c-quads
      int xx = flat >> 5, c4 = flat & 31;  // lanes vary c -> coalesced writes
      *(ushort4*)(dst + xx * 128 + c4 * 4) = *(const ushort4*)&tile[xx][c4 * 4];
    }
  } else if (blk < 1088) {  // main-weight A fragments
    int idx = (blk - 512) * 256 + tid;   // < 147456
    int jj = idx & 7, l = (idx >> 3) & 63, ks = (idx >> 9) & 3,
        mt = (idx >> 11) & 7, t = idx >> 14;
    int o = mt * 16 + (l & 15);
    int c = ks * 32 + (l >> 4) * 8 + jj;
    ((u16*)(wsb + WF_B))[idx] = f2bf(wgt[(o * 128 + c) * 9 + t]);
  } else if (blk < 1232) {  // offmask-weight A fragments (27 rows pad to 32)
    int idx = (blk - 1088) * 256 + tid;  // < 36864
    int jj = idx & 7, l = (idx >> 3) & 63, mt = (idx >> 9) & 1, ks = idx >> 10;
    int oc = mt * 16 + (l & 15);
    int k = ks * 32 + (l >> 4) * 8 + jj;
    int t = k >> 7, c = k & 127;
    float v = 0.f;
    if (oc < 18) v = ow[(oc * 128 + c) * 9 + t];
    else if (oc < 27) v = mw[((oc - 18) * 128 + c) * 9 + t];
    ((u16*)(wsb + WRF_B))[idx] = f2bf(v);
  } else {
    if (tid < 128) {
      float s = gam[tid] * rsqrtf(var[tid] + 1e-5f);
      ((float*)(wsb + BNS_B))[tid] = s;
      ((float*)(wsb + BNB_B))[tid] = bet[tid] - mean[tid] * s;
    }
  }
}

// ---------------------------------------------------------------------------
// main (fused): per block = (b, ho, half) -> 32 positions x all 128 O.
// Phase 1 (waves 0-3): offset/mask 3x3 conv via MFMA, im2col B direct from
//   XT, results (18 offsets + 9 sigmoided masks per position) -> LDS.
// Phase 2 (all 8 waves): sample all 9 taps into frag-blocked LDS (zero-
//   conflict lane-contiguous layout).
// Phase 3: 72 back-to-back MFMAs per wave (no barriers), BN+SiLU epilogue.
// Grid 512 x 512 threads. Only 2 __syncthreads total.
// ---------------------------------------------------------------------------
__global__ __launch_bounds__(512, 4) void main_kernel(
    const char* __restrict__ wsb, const float* __restrict__ ob,
    const float* __restrict__ mb, float* __restrict__ out) {
  __shared__ uint4 vbuf[72 * 64];    // 73728 B: [frag(t,nt,ks)][lane] 16B
  __shared__ float soff[32][28];     // per-position offsets+masks

  int blk = blockIdx.x;
  int b = blk >> 7, ho = (blk >> 1) & 63, half = blk & 1;
  int p0 = half * 32;
  int tid = threadIdx.x;
  int w = tid >> 6, l = tid & 63, quad = l >> 4, pn = l & 15;

  const u16* XT = (const u16*)(wsb + XT_B);
  const bf16x8* WFv = (const bf16x8*)(wsb + WF_B);
  const bf16x8* WRFv = (const bf16x8*)(wsb + WRF_B);
  bf16x8 bz = {0, 0, 0, 0, 0, 0, 0, 0};

  // ---- phase 1: offset/mask GEMM (waves 0-3), M=32(27), K=1152, N=32 ----
  if (w < 4) {
    int mt = w >> 1, ntw = w & 1;
    int p = ntw * 16 + pn;
    f32x4 acc = {0.f, 0.f, 0.f, 0.f};
#pragma unroll
    for (int t = 0; t < 9; ++t) {
      int y = ho + t / 3 - 1;
      int xx = p0 + p + t % 3 - 1;
      bool valid = ((unsigned)y < 64u) && ((unsigned)xx < 64u);
      const u16* bp = XT + ((b * 64 + y) * 64 + xx) * 128 + quad * 8;
#pragma unroll
      for (int kq = 0; kq < 4; ++kq) {
        bf16x8 a = WRFv[((t * 4 + kq) * 2 + mt) * 64 + l];
        bf16x8 bb = valid ? *(const bf16x8*)(bp + kq * 32) : bz;
        acc = __builtin_amdgcn_mfma_f32_16x16x32_bf16(a, bb, acc, 0, 0, 0);
      }
    }
#pragma unroll
    for (int r = 0; r < 4; ++r) {
      int oc = mt * 16 + quad * 4 + r;  // D: col=lane&15, row=quad*4+reg
      if (oc < 27) {
        float v = acc[r] + (oc < 18 ? ob[oc] : mb[oc - 18]);
        if (oc >= 18) v = 1.f / (1.f + __expf(-v));  // pre-sigmoid masks
        soff[p][oc] = v;
      }
    }
  }
  __syncthreads();

  // ---- phase 2: sample all 9 taps into LDS fragments ----
  // wave w covers frag column (nt = w>>2, ks = w&3) for every tap t.
  {
    int nt_s = (w >> 2) & 1, ks_s = w & 3;
    int p_s = nt_s * 16 + pn;
    const u16* xb = XT + (size_t)b * 64 * 64 * 128 + ks_s * 32 + quad * 8;
    uint4 z = make_uint4(0, 0, 0, 0);
#pragma unroll
    for (int t = 0; t < 9; ++t) {
      float oy = soff[p_s][2 * t], ox = soff[p_s][2 * t + 1];
      float m = soff[p_s][18 + t];
      float py = (float)(ho + t / 3 - 1) + oy;
      float px = (float)(p0 + p_s + t % 3 - 1) + ox;
      float y0f = floorf(py), x0f = floorf(px);
      int y0 = (int)y0f, x0 = (int)x0f;
      float ly = py - y0f, lx = px - x0f;
      bool yv0 = (unsigned)y0 < 64u, yv1 = (unsigned)(y0 + 1) < 64u;
      bool xv0 = (unsigned)x0 < 64u, xv1 = (unsigned)(x0 + 1) < 64u;
      const u16* r0 = xb + (y0 * 64 + x0) * 128;
      uint4 q00 = (yv0 && xv0) ? *(const uint4*)(r0) : z;
      uint4 q01 = (yv0 && xv1) ? *(const uint4*)(r0 + 128) : z;
      uint4 q10 = (yv1 && xv0) ? *(const uint4*)(r0 + 8192) : z;
      uint4 q11 = (yv1 && xv1) ? *(const uint4*)(r0 + 8320) : z;
      float w00 = (1.f - ly) * (1.f - lx) * m, w01 = (1.f - ly) * lx * m;
      float w10 = ly * (1.f - lx) * m,        w11 = ly * lx * m;
      uint4 o;
      o.x = pk(w00 * ulo(q00.x) + w01 * ulo(q01.x) + w10 * ulo(q10.x) + w11 * ulo(q11.x),
               w00 * uhi(q00.x) + w01 * uhi(q01.x) + w10 * uhi(q10.x) + w11 * uhi(q11.x));
      o.y = pk(w00 * ulo(q00.y) + w01 * ulo(q01.y) + w10 * ulo(q10.y) + w11 * ulo(q11.y),
               w00 * uhi(q00.y) + w01 * uhi(q01.y) + w10 * uhi(q10.y) + w11 * uhi(q11.y));
      o.z = pk(w00 * ulo(q00.z) + w01 * ulo(q01.z) + w10 * ulo(q10.z) + w11 * ulo(q11.z),
               w00 * uhi(q00.z) + w01 * uhi(q01.z) + w10 * uhi(q10.z) + w11 * uhi(q11.z));
      o.w = pk(w00 * ulo(q00.w) + w01 * ulo(q01.w) + w10 * ulo(q10.w) + w11 * ulo(q11.w),
               w00 * uhi(q00.w) + w01 * uhi(q01.w) + w10 * uhi(q10.w) + w11 * uhi(q11.w));
      vbuf[((t * 8 + nt_s * 4 + ks_s) * 64) + l] = o;  // lane-contiguous
    }
  }
  __syncthreads();

  // ---- phase 3: main GEMM, wave w -> O-tile mt=w, both nt halves ----
  const bf16x8* vbf = (const bf16x8*)vbuf;
  f32x4 acc0 = {0.f, 0.f, 0.f, 0.f}, acc1 = {0.f, 0.f, 0.f, 0.f};
#pragma unroll
  for (int t = 0; t < 9; ++t) {
#pragma unroll
    for (int ks = 0; ks < 4; ++ks) {
      bf16x8 a = WFv[((t * 8 + w) * 4 + ks) * 64 + l];
      bf16x8 b0 = vbf[(t * 8 + ks) * 64 + l];
      bf16x8 b1 = vbf[(t * 8 + 4 + ks) * 64 + l];
      acc0 = __builtin_amdgcn_mfma_f32_16x16x32_bf16(a, b0, acc0, 0, 0, 0);
      acc1 = __builtin_amdgcn_mfma_f32_16x16x32_bf16(a, b1, acc1, 0, 0, 0);
    }
  }

  // ---- epilogue: BN + SiLU ----
  const float* BNS = (const float*)(wsb + BNS_B);
  const float* BNB = (const float*)(wsb + BNB_B);
#pragma unroll
  for (int nt = 0; nt < 2; ++nt) {
    f32x4 acc = nt ? acc1 : acc0;
#pragma unroll
    for (int r = 0; r < 4; ++r) {
      int o = w * 16 + quad * 4 + r;
      float v = acc[r] * BNS[o] + BNB[o];
      v = v / (1.f + __expf(-v));
      out[((b * 128 + o) * 64 + ho) * 64 + p0 + nt * 16 + pn] = v;
    }
  }
}

extern "C" void kernel_launch(void* const* d_in, const int* in_sizes, int n_in,
                              void* d_out, int out_size, void* d_ws, size_t ws_size,
                              hipStream_t stream) {
  const float* x    = (const float*)d_in[0];
  const float* ow   = (const float*)d_in[1];
  const float* ob   = (const float*)d_in[2];
  const float* mw   = (const float*)d_in[3];
  const float* mb   = (const float*)d_in[4];
  const float* wgt  = (const float*)d_in[5];
  const float* gam  = (const float*)d_in[6];
  const float* bet  = (const float*)d_in[7];
  const float* mean = (const float*)d_in[8];
  const float* var  = (const float*)d_in[9];
  char* wsb = (char*)d_ws;
  float* out = (float*)d_out;

  prep_kernel<<<1233, 256, 0, stream>>>(x, ow, mw, wgt, gam, bet, mean, var, wsb);
  main_kernel<<<512, 512, 0, stream>>>(wsb, ob, mb, out);
}

// Round 4
// 105.245 us; speedup vs baseline: 1.5214x; 1.5214x over previous
//
#include <hip/hip_runtime.h>
#include <math.h>

typedef unsigned short u16;
typedef short bf16x8 __attribute__((ext_vector_type(8)));
typedef float f32x4 __attribute__((ext_vector_type(4)));

// Workspace byte offsets
#define XT_B   0u          // bf16 [4][64][64][128]  NHWC x
#define WF_B   4194304u    // bf16 [9][8][4][64][8]  main A-frags (t,mt,ks,lane,j)
#define WRF_B  4489216u    // bf16 [36][2][64][8]    offmask A-frags (ks',mt,lane,j)
#define BNS_B  4562944u    // f32 [128] folded BN scale
#define BNB_B  4563456u    // f32 [128] folded BN shift

__device__ __forceinline__ u16 f2bf(float f) {
  union { float f; unsigned int i; } v; v.f = f;
  unsigned int i = v.i;
  return (u16)((i + 0x7fffu + ((i >> 16) & 1u)) >> 16);  // RNE
}
__device__ __forceinline__ float ulo(unsigned int u) {
  union { unsigned int i; float f; } v; v.i = u << 16; return v.f;
}
__device__ __forceinline__ float uhi(unsigned int u) {
  union { unsigned int i; float f; } v; v.i = u & 0xffff0000u; return v.f;
}
__device__ __forceinline__ unsigned int pk(float lo, float hi) {
  return (unsigned int)f2bf(lo) | ((unsigned int)f2bf(hi) << 16);
}

// ---------------------------------------------------------------------------
// prep: x -> bf16 NHWC (float4 reads, LDS transpose), weight frag shuffles,
// BN fold. Grid = 1233 x 256.
// ---------------------------------------------------------------------------
__global__ __launch_bounds__(256) void prep_kernel(
    const float* __restrict__ x,   const float* __restrict__ ow,
    const float* __restrict__ mw,  const float* __restrict__ wgt,
    const float* __restrict__ gam, const float* __restrict__ bet,
    const float* __restrict__ mean,const float* __restrict__ var,
    char* __restrict__ wsb) {
  int blk = blockIdx.x, tid = threadIdx.x;
  if (blk < 512) {  // transpose 128c x 32x half-plane -> 32x x 128c bf16
    __shared__ u16 tile[32][136];  // pitch 272B: 16B-aligned, bank-staggered
    int b = blk >> 7, y = (blk >> 1) & 63, xh = blk & 1;
    const float* src = x + (size_t)b * 524288 + y * 64 + xh * 32;
#pragma unroll
    for (int r = 0; r < 4; ++r) {
      int flat = r * 256 + tid;          // 1024 = 128c x 8 x4-groups
      int c = flat >> 3, x4 = (flat & 7) * 4;
      float4 v = *(const float4*)(src + c * 4096 + x4);  // coalesced 128B/8 lanes
      tile[x4 + 0][c] = f2bf(v.x);
      tile[x4 + 1][c] = f2bf(v.y);
      tile[x4 + 2][c] = f2bf(v.z);
      tile[x4 + 3][c] = f2bf(v.w);
    }
    __syncthreads();
    u16* dst = (u16*)(wsb + XT_B) + ((b * 64 + y) * 64 + xh * 32) * 128;
#pragma unroll
    for (int r = 0; r < 2; ++r) {
      int flat = r * 256 + tid;          // 512 = 32x x 16 c8-groups
      int xx = flat >> 4, c8 = (flat & 15) * 8;
      *(uint4*)(dst + xx * 128 + c8) = *(const uint4*)&tile[xx][c8];  // 256B/16 lanes
    }
  } else if (blk < 1088) {  // main-weight A fragments
    int idx = (blk - 512) * 256 + tid;   // < 147456
    int jj = idx & 7, l = (idx >> 3) & 63, ks = (idx >> 9) & 3,
        mt = (idx >> 11) & 7, t = idx >> 14;
    int o = mt * 16 + (l & 15);
    int c = ks * 32 + (l >> 4) * 8 + jj;
    ((u16*)(wsb + WF_B))[idx] = f2bf(wgt[(o * 128 + c) * 9 + t]);
  } else if (blk < 1232) {  // offmask-weight A fragments (27 rows pad to 32)
    int idx = (blk - 1088) * 256 + tid;  // < 36864
    int jj = idx & 7, l = (idx >> 3) & 63, mt = (idx >> 9) & 1, ks = idx >> 10;
    int oc = mt * 16 + (l & 15);
    int k = ks * 32 + (l >> 4) * 8 + jj;
    int t = k >> 7, c = k & 127;
    float v = 0.f;
    if (oc < 18) v = ow[(oc * 128 + c) * 9 + t];
    else if (oc < 27) v = mw[((oc - 18) * 128 + c) * 9 + t];
    ((u16*)(wsb + WRF_B))[idx] = f2bf(v);
  } else {
    if (tid < 128) {
      float s = gam[tid] * rsqrtf(var[tid] + 1e-5f);
      ((float*)(wsb + BNS_B))[tid] = s;
      ((float*)(wsb + BNB_B))[tid] = bet[tid] - mean[tid] * s;
    }
  }
}

// ---------------------------------------------------------------------------
// main (fused): block = (b, ho, quarter) -> 16 positions x 128 O.
// P1: offset/mask conv, all 4 waves (K split), partials in LDS (aliases vbuf).
// P2: branchless clamped-gather sampling, 16 ch-lanes x 4 pos per wave.
// P3: 72 MFMA/wave with explicit A-frag double-buffer. 3 barriers total.
// Grid 1024 x 256. LDS 39.2 KB -> 4 blocks/CU.
// ---------------------------------------------------------------------------
__global__ __launch_bounds__(256, 4) void main_kernel(
    const char* __restrict__ wsb, const float* __restrict__ ob,
    const float* __restrict__ mb, float* __restrict__ out) {
  __shared__ __align__(16) char smem[16 * 1160 * 2];  // 37120 B
  __shared__ float soff[16][32];
  u16* vbuf = (u16*)smem;      // [16][1160] sampled values (phase 2/3)
  float* pred = (float*)smem;  // [2][2][16][16] conv partials (phase 1)

  int blk = blockIdx.x;
  int b = blk >> 8, ho = (blk >> 2) & 63, qd = blk & 3;
  int p0 = qd * 16;
  int tid = threadIdx.x;
  int w = tid >> 6, l = tid & 63, quad = l >> 4, pn = l & 15;

  const u16* XT = (const u16*)(wsb + XT_B);
  const bf16x8* WFv = (const bf16x8*)(wsb + WF_B);
  const bf16x8* WRFv = (const bf16x8*)(wsb + WRF_B);
  bf16x8 bz = {0, 0, 0, 0, 0, 0, 0, 0};

  // ---- phase 1: offset/mask conv partials; wave = (kh=w>>1, mt=w&1) ----
  {
    int mt = w & 1, kh = w >> 1;
    f32x4 acc = {0.f, 0.f, 0.f, 0.f};
#pragma unroll
    for (int t = 0; t < 9; ++t) {
      int y = ho + t / 3 - 1;
      int xx = p0 + pn + t % 3 - 1;
      bool valid = ((unsigned)y < 64u) && ((unsigned)xx < 64u);
      const u16* bp = XT + ((b * 64 + y) * 64 + xx) * 128 + quad * 8;
#pragma unroll
      for (int kqi = 0; kqi < 2; ++kqi) {
        int kq = kh * 2 + kqi;
        bf16x8 a = WRFv[((t * 4 + kq) * 2 + mt) * 64 + l];
        bf16x8 bb = valid ? *(const bf16x8*)(bp + kq * 32) : bz;
        acc = __builtin_amdgcn_mfma_f32_16x16x32_bf16(a, bb, acc, 0, 0, 0);
      }
    }
#pragma unroll
    for (int r = 0; r < 4; ++r)
      pred[((kh * 2 + mt) * 16 + quad * 4 + r) * 16 + pn] = acc[r];
  }
  __syncthreads();
  // reduce K-halves, add bias, sigmoid masks -> soff[p][oc]
  for (int i = tid; i < 432; i += 256) {
    int oc = i >> 4, p = i & 15;
    int mt = oc >> 4, row = oc & 15;
    float v = pred[(mt * 16 + row) * 16 + p] + pred[((2 + mt) * 16 + row) * 16 + p]
            + (oc < 18 ? ob[oc] : mb[oc - 18]);
    if (oc >= 18) v = 1.f / (1.f + __expf(-v));
    soff[p][oc] = v;
  }
  __syncthreads();

  // ---- phase 2: sampling, branchless clamped gathers ----
  {
    int cl = l & 15, pi = l >> 4;
    int p = w * 4 + pi;
    const u16* xb = XT + (size_t)b * 524288 + cl * 8;
#pragma unroll
    for (int t = 0; t < 9; ++t) {
      float oy = soff[p][2 * t], ox = soff[p][2 * t + 1], m = soff[p][18 + t];
      float py = (float)(ho + t / 3 - 1) + oy;
      float px = (float)(p0 + p + t % 3 - 1) + ox;
      float y0f = floorf(py), x0f = floorf(px);
      int y0 = (int)y0f, x0 = (int)x0f;
      float ly = py - y0f, lx = px - x0f;
      float vy0 = (y0 >= 0 && y0 < 64) ? 1.f : 0.f;
      float vy1 = (y0 >= -1 && y0 < 63) ? 1.f : 0.f;
      float vx0 = (x0 >= 0 && x0 < 64) ? 1.f : 0.f;
      float vx1 = (x0 >= -1 && x0 < 63) ? 1.f : 0.f;
      int y0c = min(max(y0, 0), 63), y1c = min(max(y0 + 1, 0), 63);
      int x0c = min(max(x0, 0), 63), x1c = min(max(x0 + 1, 0), 63);
      // always-execute loads (clamped): pure dataflow, schedulable across taps
      uint4 q00 = *(const uint4*)(xb + (y0c * 64 + x0c) * 128);
      uint4 q01 = *(const uint4*)(xb + (y0c * 64 + x1c) * 128);
      uint4 q10 = *(const uint4*)(xb + (y1c * 64 + x0c) * 128);
      uint4 q11 = *(const uint4*)(xb + (y1c * 64 + x1c) * 128);
      float w00 = (1.f - ly) * (1.f - lx) * m * vy0 * vx0;
      float w01 = (1.f - ly) * lx * m * vy0 * vx1;
      float w10 = ly * (1.f - lx) * m * vy1 * vx0;
      float w11 = ly * lx * m * vy1 * vx1;
      uint4 o;
      o.x = pk(w00 * ulo(q00.x) + w01 * ulo(q01.x) + w10 * ulo(q10.x) + w11 * ulo(q11.x),
               w00 * uhi(q00.x) + w01 * uhi(q01.x) + w10 * uhi(q10.x) + w11 * uhi(q11.x));
      o.y = pk(w00 * ulo(q00.y) + w01 * ulo(q01.y) + w10 * ulo(q10.y) + w11 * ulo(q11.y),
               w00 * uhi(q00.y) + w01 * uhi(q01.y) + w10 * uhi(q10.y) + w11 * uhi(q11.y));
      o.z = pk(w00 * ulo(q00.z) + w01 * ulo(q01.z) + w10 * ulo(q10.z) + w11 * ulo(q11.z),
               w00 * uhi(q00.z) + w01 * uhi(q01.z) + w10 * uhi(q10.z) + w11 * uhi(q11.z));
      o.w = pk(w00 * ulo(q00.w) + w01 * ulo(q01.w) + w10 * ulo(q10.w) + w11 * ulo(q11.w),
               w00 * uhi(q00.w) + w01 * uhi(q01.w) + w10 * uhi(q10.w) + w11 * uhi(q11.w));
      *(uint4*)&vbuf[p * 1160 + t * 128 + cl * 8] = o;
    }
  }
  __syncthreads();

  // ---- phase 3: GEMM, wave w -> O-tiles {2w, 2w+1}, A double-buffered ----
  f32x4 acc0 = {0.f, 0.f, 0.f, 0.f}, acc1 = {0.f, 0.f, 0.f, 0.f};
  bf16x8 A0[2][4], A1[2][4];
#pragma unroll
  for (int ks = 0; ks < 4; ++ks) {
    A0[0][ks] = WFv[((0 * 8 + 2 * w) * 4 + ks) * 64 + l];
    A1[0][ks] = WFv[((0 * 8 + 2 * w + 1) * 4 + ks) * 64 + l];
  }
#pragma unroll
  for (int t = 0; t < 9; ++t) {
    int cur = t & 1, nxt = cur ^ 1;
    if (t < 8) {
#pragma unroll
      for (int ks = 0; ks < 4; ++ks) {
        A0[nxt][ks] = WFv[(((t + 1) * 8 + 2 * w) * 4 + ks) * 64 + l];
        A1[nxt][ks] = WFv[(((t + 1) * 8 + 2 * w + 1) * 4 + ks) * 64 + l];
      }
    }
#pragma unroll
    for (int ks = 0; ks < 4; ++ks) {
      bf16x8 bfr = *(const bf16x8*)&vbuf[pn * 1160 + t * 128 + ks * 32 + quad * 8];
      acc0 = __builtin_amdgcn_mfma_f32_16x16x32_bf16(A0[cur][ks], bfr, acc0, 0, 0, 0);
      acc1 = __builtin_amdgcn_mfma_f32_16x16x32_bf16(A1[cur][ks], bfr, acc1, 0, 0, 0);
    }
  }

  // ---- epilogue: BN + SiLU ----
  const float* BNS = (const float*)(wsb + BNS_B);
  const float* BNB = (const float*)(wsb + BNB_B);
#pragma unroll
  for (int mi = 0; mi < 2; ++mi) {
    f32x4 acc = mi ? acc1 : acc0;
#pragma unroll
    for (int r = 0; r < 4; ++r) {
      int o = (2 * w + mi) * 16 + quad * 4 + r;
      float v = acc[r] * BNS[o] + BNB[o];
      v = v / (1.f + __expf(-v));
      out[((b * 128 + o) * 64 + ho) * 64 + p0 + pn] = v;
    }
  }
}

extern "C" void kernel_launch(void* const* d_in, const int* in_sizes, int n_in,
                              void* d_out, int out_size, void* d_ws, size_t ws_size,
                              hipStream_t stream) {
  const float* x    = (const float*)d_in[0];
  const float* ow   = (const float*)d_in[1];
  const float* ob   = (const float*)d_in[2];
  const float* mw   = (const float*)d_in[3];
  const float* mb   = (const float*)d_in[4];
  const float* wgt  = (const float*)d_in[5];
  const float* gam  = (const float*)d_in[6];
  const float* bet  = (const float*)d_in[7];
  const float* mean = (const float*)d_in[8];
  const float* var  = (const float*)d_in[9];
  char* wsb = (char*)d_ws;
  float* out = (float*)d_out;

  prep_kernel<<<1233, 256, 0, stream>>>(x, ow, mw, wgt, gam, bet, mean, var, wsb);
  main_kernel<<<1024, 256, 0, stream>>>(wsb, ob, mb, out);
}